// Round 7
// baseline (320.086 us; speedup 1.0000x reference)
//
#include <hip/hip_runtime.h>
#include <stdint.h>

#define NB 16
#define CC 32
#define HH 224
#define WW 224
#define HWP (HH*WW)          // 50176
#define NHWP (NB*HWP)        // 802816
#define PW 226
#define PSZ (PW*PW)          // 51076 padded words per image

// workspace layout (bytes)
#define OFF_S1   0u
#define OFF_S2   3268864u    // 16*51076*4
#define OFF_WP1  6537728u
#define OFF_WP2  6538880u
#define OFF_SQ1  6540032u    // 16 bins x 32 x u64
#define OFF_SQ2  6544128u
#define OFF_SUM1 6548224u    // 16 bins x 32 x i32
#define OFF_SUM2 6550272u    // end 6552320

typedef int v4i    __attribute__((ext_vector_type(4)));
typedef int i32x16 __attribute__((ext_vector_type(16)));

// ============ setup: pack weights, zero stats bins, zero pad borders of s1/s2 ============
__global__ void __launch_bounds__(256) k_setup(const uint32_t* __restrict__ w1,
                                               const uint32_t* __restrict__ w2,
                                               char* __restrict__ ws) {
    int t = blockIdx.x * 256 + threadIdx.x;
    if (t < 576) {
        const uint32_t* w = (t < 288) ? w1 : w2;
        uint32_t* o = (uint32_t*)(ws + ((t < 288) ? OFF_WP1 : OFF_WP2));
        int idx = (t < 288) ? t : t - 288;
        int oc = idx / 9, k = idx - oc * 9;
        uint32_t word = 0;
        for (int i = 0; i < 32; ++i)
            word |= (w[(oc * 32 + i) * 9 + k] >> 31) << i;
        o[idx] = word;
    } else if (t < 3648) {
        // 3072 words: sq1(1024) sq2(1024) sum1(512) sum2(512), contiguous
        ((uint32_t*)(ws + OFF_SQ1))[t - 576] = 0u;
    } else if (t >= 4096 && t < 4096 + 28800) {
        int b = t - 4096;
        uint32_t* buf = (uint32_t*)(ws + ((b < 14400) ? OFF_S1 : OFF_S2));
        int bb = (b < 14400) ? b : b - 14400;
        int n = bb / 900;
        int e = bb - n * 900;
        int row, col;
        if (e < 226)      { row = 0;   col = e; }
        else if (e < 452) { row = 225; col = e - 226; }
        else { int k = e - 452; row = 1 + (k >> 1); col = (k & 1) ? 225 : 0; }
        buf[(size_t)n * PSZ + row * PW + col] = 0u;
    }
}

// ============ pack activation signs into padded layout ============
__global__ void __launch_bounds__(256) k_packx(const uint32_t* __restrict__ x,
                                               uint32_t* __restrict__ sp) {
    int t = blockIdx.x * 256 + threadIdx.x;        // 16 * 12544 threads, 4 px each
    int n = t / (HWP / 4);
    int rem4 = t - n * (HWP / 4);
    int px0 = rem4 * 4;
    int r = px0 / WW;
    int cw0 = px0 - r * WW;
    const uint32_t* xp = x + (size_t)n * CC * HWP + px0;
    uint32_t w0 = 0, w1 = 0, w2 = 0, w3 = 0;
    #pragma unroll
    for (int c = 0; c < 32; ++c) {
        uint4 v = *reinterpret_cast<const uint4*>(xp + (size_t)c * HWP);
        w0 |= (v.x >> 31) << c;
        w1 |= (v.y >> 31) << c;
        w2 |= (v.z >> 31) << c;
        w3 |= (v.w >> 31) << c;
    }
    uint32_t* op = sp + (size_t)n * PSZ + (r + 1) * PW + (cw0 + 1);
    op[0] = w0; op[1] = w1; op[2] = w2; op[3] = w3;
}

// ============ MFMA conv core (layers 1 & 2) ============
// Block = 448 threads = 7 waves; block handles one full row r of image n.
// Wave w computes out px [32w, 32w+32) x 32 oc via 9x mfma_i32_32x32x32_i8.
// A tile in LDS: 3 rows x 226 cols of decoded +/-1 i8 (pad -> 0), 48 B/px slot.
// A lane map (M=px): row = lane%32, k(ic) = 16*(lane/32) + [0..15]
// B lane map (N=oc): col = lane%32, k(ic) = 16*(lane/32) + [0..15]
// C/D: col(oc) = lane&31, row(px) = (reg&3) + 8*(reg>>2) + 4*(lane>>5)
#define ASTRIDE 48
#define AROW (226*ASTRIDE)

__device__ __forceinline__ uint32_t spread4(uint32_t nib) {
    // 4 sign bits -> 4 bytes of +1 / -1 (0x01 / 0xFF).
    // s has bit0 of each byte = sign bit; s*0xFE is byte-confined (no carry),
    // and 0x01 ^ 0xFE = 0xFF.  (0x01010101 - 2*s is WRONG: byte borrows.)
    uint32_t s = (nib & 1u) | ((nib & 2u) << 7) | ((nib & 4u) << 14) | ((nib & 8u) << 21);
    return 0x01010101u ^ (s * 0xFEu);
}

__device__ __forceinline__ i32x16 conv_mfma(const uint32_t* __restrict__ sp,
                                            const uint32_t* __restrict__ wp,
                                            int n, int r, char* At) {
    // stage + decode 3 rows incl. 1-px halo; out-of-image -> 0 bytes
    for (int s = threadIdx.x; s < 3 * 226; s += 448) {
        int dr = s / 226, cc = s - dr * 226;
        int srow = r - 1 + dr, scol = cc - 1;
        uint32_t d8[8];
        if (srow < 0 || srow >= HH || scol < 0 || scol >= WW) {
            #pragma unroll
            for (int i = 0; i < 8; ++i) d8[i] = 0u;
        } else {
            uint32_t w = sp[(size_t)n * PSZ + (srow + 1) * PW + (scol + 1)];
            #pragma unroll
            for (int i = 0; i < 8; ++i) d8[i] = spread4((w >> (4 * i)) & 0xFu);
        }
        uint32_t* p = (uint32_t*)(At + s * ASTRIDE);
        *(uint4*)(p)     = make_uint4(d8[0], d8[1], d8[2], d8[3]);
        *(uint4*)(p + 4) = make_uint4(d8[4], d8[5], d8[6], d8[7]);
    }

    // per-lane weight B-fragments for the 9 taps (from packed words, L1-cached)
    int l = threadIdx.x & 63;
    int oc = l & 31, kb = (l >> 5) * 16;
    v4i bf[9];
    #pragma unroll
    for (int t = 0; t < 9; ++t) {
        uint32_t w = wp[oc * 9 + t];
        uint32_t r0 = spread4((w >> (kb))      & 0xFu);
        uint32_t r1 = spread4((w >> (kb + 4))  & 0xFu);
        uint32_t r2 = spread4((w >> (kb + 8))  & 0xFu);
        uint32_t r3 = spread4((w >> (kb + 12)) & 0xFu);
        bf[t] = v4i{(int)r0, (int)r1, (int)r2, (int)r3};
    }
    __syncthreads();

    int wavebase = (threadIdx.x >> 6) * 32;
    int base = (wavebase + (l & 31)) * ASTRIDE + (l >> 5) * 16;

    i32x16 acc = {0,0,0,0,0,0,0,0,0,0,0,0,0,0,0,0};
    #pragma unroll
    for (int dh = 0; dh < 3; ++dh) {
        #pragma unroll
        for (int dw = 0; dw < 3; ++dw) {
            v4i a = *reinterpret_cast<const v4i*>(At + base + dh * AROW + dw * ASTRIDE);
            acc = __builtin_amdgcn_mfma_i32_32x32x32_i8(a, bf[dh * 3 + dw], acc, 0, 0, 0);
        }
    }
    return acc;
}

// ============ conv (MFMA) + exact per-channel sum / sumsq into 16 bins ============
__global__ void __launch_bounds__(448) k_stats(const uint32_t* __restrict__ sp,
                                               const uint32_t* __restrict__ wp,
                                               int* __restrict__ g_sum,
                                               unsigned long long* __restrict__ g_sq) {
    __shared__ __align__(16) char At[3 * 226 * ASTRIDE];
    __shared__ int ls[7][32], lq[7][32];

    int n = blockIdx.x / HH, r = blockIdx.x - n * HH;
    i32x16 acc = conv_mfma(sp, wp, n, r, At);

    int l = threadIdx.x & 63;
    int s = 0, q = 0;
    #pragma unroll
    for (int g = 0; g < 16; ++g) { int c = acc[g]; s += c; q += c * c; }
    s += __shfl_xor(s, 32, 64);      // merge half-wave px groups; lane&31 owns oc
    q += __shfl_xor(q, 32, 64);
    int wid = threadIdx.x >> 6;
    if (l < 32) { ls[wid][l] = s; lq[wid][l] = q; }
    __syncthreads();
    if (threadIdx.x < 32) {
        int S = 0, Q = 0;
        #pragma unroll
        for (int w = 0; w < 7; ++w) { S += ls[w][threadIdx.x]; Q += lq[w][threadIdx.x]; }
        int bin = blockIdx.x & 15;
        atomicAdd(&g_sum[bin * 32 + threadIdx.x], S);
        atomicAdd(&g_sq[bin * 32 + threadIdx.x], (unsigned long long)(long long)Q);
    }
}

// ============ BN affine from 16-bin exact int stats ============
__device__ __forceinline__ void build_affine16(const int* __restrict__ g_sum,
                                               const unsigned long long* __restrict__ g_sq,
                                               const float* __restrict__ gamma,
                                               const float* __restrict__ beta,
                                               float* aL, float* dL) {
    if (threadIdx.x < 32) {
        int c = threadIdx.x;
        int Si = 0; unsigned long long Qu = 0;
        #pragma unroll
        for (int b = 0; b < 16; ++b) { Si += g_sum[b * 32 + c]; Qu += g_sq[b * 32 + c]; }
        double M = (double)NHWP;
        double mean = (double)Si / M;
        double ex2 = (double)(long long)Qu / M;
        double var = ex2 - mean * mean;
        double inv = 1.0 / sqrt(var + 1e-5);
        double aa = inv * (double)gamma[c];
        aL[c] = (float)aa;
        dL[c] = (float)((double)beta[c] - aa * mean);
    }
}

// ============ conv1 (MFMA) + BN1 + sign -> packed padded s2 via ballot ============
__global__ void __launch_bounds__(448) k_sign(const uint32_t* __restrict__ sp,
                                              const uint32_t* __restrict__ wp,
                                              const int* __restrict__ g_sum,
                                              const unsigned long long* __restrict__ g_sq,
                                              const float* __restrict__ gamma,
                                              const float* __restrict__ beta,
                                              uint32_t* __restrict__ op) {
    __shared__ __align__(16) char At[3 * 226 * ASTRIDE];
    __shared__ float aL[32], dL[32];
    build_affine16(g_sum, g_sq, gamma, beta, aL, dL);

    int n = blockIdx.x / HH, r = blockIdx.x - n * HH;
    i32x16 acc = conv_mfma(sp, wp, n, r, At);

    int l = threadIdx.x & 63;
    int wavebase = (threadIdx.x >> 6) * 32;
    float a = aL[l & 31], d = dL[l & 31];
    uint32_t* orow = op + (size_t)n * PSZ + (r + 1) * PW + 1 + wavebase;
    #pragma unroll
    for (int g = 0; g < 16; ++g) {
        float y = fmaf(a, (float)acc[g], d);
        unsigned long long b = __ballot((__float_as_uint(y) >> 31) != 0u);
        if (l == 0) {
            int pxr = (g & 3) + 8 * (g >> 2);   // lanes 0-31 px row; +4 for lanes 32-63
            orow[pxr]     = (uint32_t)b;
            orow[pxr + 4] = (uint32_t)(b >> 32);
        }
    }
}

// ============ conv2 + BN2 + residual (proven popc path, HBM-bound) ============
__device__ __forceinline__ void stage_lds(const uint32_t* __restrict__ wp,
                                          uint32_t (*Wl)[12], int (*Ctab)[32]) {
    for (int i = threadIdx.x; i < 288; i += 256) {
        int oc = i / 9, k = i - oc * 9;
        Wl[oc][k] = wp[i];
    }
    for (int i = threadIdx.x; i < 512; i += 256) {
        int ty = i >> 5, oc = i & 31;
        int s = 0;
        #pragma unroll
        for (int t = 0; t < 9; ++t) {
            int dh = t / 3 - 1, dw = t % 3 - 1;
            bool pad = ((ty & 1) && dh < 0) || ((ty & 2) && dh > 0) ||
                       ((ty & 4) && dw < 0) || ((ty & 8) && dw > 0);
            if (pad) s += 32 - 2 * __popc(wp[oc * 9 + t]);
        }
        Ctab[ty][oc] = s;
    }
}

__device__ __forceinline__ void decode_grp(int t, int& n, int& r, int& cw0) {
    n = t / 12544;
    int rem = t - n * 12544;
    r = rem / 56;
    cw0 = (rem - r * 56) * 4;
}

#define LOAD_TAPS18(base)                                                        \
    uint32_t u0 = (base)[-PW-1], u1 = (base)[-PW],   u2 = (base)[-PW+1],         \
             u3 = (base)[-PW+2], u4 = (base)[-PW+3], u5 = (base)[-PW+4];         \
    uint32_t m0 = (base)[-1],    m1 = (base)[0],     m2 = (base)[1],             \
             m3 = (base)[2],     m4 = (base)[3],     m5 = (base)[4];             \
    uint32_t l0 = (base)[PW-1],  l1 = (base)[PW],    l2 = (base)[PW+1],          \
             l3 = (base)[PW+2],  l4 = (base)[PW+3],  l5 = (base)[PW+4];

#define CONV4L(oc_)                                                              \
    int ocl = (oc_);                                                             \
    asm volatile("" : "+v"(ocl));                                                \
    const uint32_t* wr = &Wl[ocl][0];                                            \
    uint32_t w0 = wr[0], w1 = wr[1], w2 = wr[2], w3 = wr[3], w4 = wr[4],         \
             w5 = wr[5], w6 = wr[6], w7 = wr[7], w8 = wr[8];                     \
    int pc0 = __popc(u0^w0)+__popc(u1^w1)+__popc(u2^w2)                          \
            + __popc(m0^w3)+__popc(m1^w4)+__popc(m2^w5)                          \
            + __popc(l0^w6)+__popc(l1^w7)+__popc(l2^w8);                         \
    int pc1 = __popc(u1^w0)+__popc(u2^w1)+__popc(u3^w2)                          \
            + __popc(m1^w3)+__popc(m2^w4)+__popc(m3^w5)                          \
            + __popc(l1^w6)+__popc(l2^w7)+__popc(l3^w8);                         \
    int pc2 = __popc(u2^w0)+__popc(u3^w1)+__popc(u4^w2)                          \
            + __popc(m2^w3)+__popc(m3^w4)+__popc(m4^w5)                          \
            + __popc(l2^w6)+__popc(l3^w7)+__popc(l4^w8);                         \
    int pc3 = __popc(u3^w0)+__popc(u4^w1)+__popc(u5^w2)                          \
            + __popc(m3^w3)+__popc(m4^w4)+__popc(m5^w5)                          \
            + __popc(l3^w6)+__popc(l4^w7)+__popc(l5^w8);                         \
    int c0 = 288 - 2*pc0 - Ctab[ty0][ocl];                                       \
    int c1 = 288 - 2*pc1 - Ctab[rb][ocl];                                        \
    int c2 = 288 - 2*pc2 - Ctab[rb][ocl];                                        \
    int c3 = 288 - 2*pc3 - Ctab[ty3][ocl];

#define DECODE_BORDER()                                                          \
    int rb = (r == 0) ? 1 : (r == HH - 1) ? 2 : 0;                               \
    int ty0 = rb | ((cw0 == 0) ? 4 : 0);                                         \
    int ty3 = rb | ((cw0 == WW - 4) ? 8 : 0);

__global__ void __launch_bounds__(256) k_res(const uint32_t* __restrict__ sp,
                                             const uint32_t* __restrict__ wp,
                                             const int* __restrict__ g_sum,
                                             const unsigned long long* __restrict__ g_sq,
                                             const float* __restrict__ gamma,
                                             const float* __restrict__ beta,
                                             const float* __restrict__ x,
                                             float* __restrict__ out) {
    __shared__ __align__(16) uint32_t Wl[32][12];
    __shared__ int Ctab[16][32];
    __shared__ float aL[32], dL[32];
    stage_lds(wp, Wl, Ctab);
    build_affine16(g_sum, g_sq, gamma, beta, aL, dL);
    __syncthreads();

    int t = blockIdx.x * 256 + threadIdx.x;        // 784 blocks, 4 px/thread
    int n, r, cw0; decode_grp(t, n, r, cw0);
    const uint32_t* base = sp + (size_t)n * PSZ + (r + 1) * PW + (cw0 + 1);
    LOAD_TAPS18(base)
    DECODE_BORDER()

    size_t pix = (size_t)n * CC * HWP + (size_t)r * WW + cw0;   // 16B aligned
    #pragma unroll
    for (int oc = 0; oc < 32; ++oc) {
        CONV4L(oc)
        float a = aL[ocl], d = dL[ocl];
        float4 xv = *reinterpret_cast<const float4*>(x + pix + (size_t)ocl * HWP);
        float4 ov;
        ov.x = xv.x + fmaf(a, (float)c0, d);
        ov.y = xv.y + fmaf(a, (float)c1, d);
        ov.z = xv.z + fmaf(a, (float)c2, d);
        ov.w = xv.w + fmaf(a, (float)c3, d);
        *reinterpret_cast<float4*>(out + pix + (size_t)ocl * HWP) = ov;
    }
}

extern "C" void kernel_launch(void* const* d_in, const int* in_sizes, int n_in,
                              void* d_out, int out_size, void* d_ws, size_t ws_size,
                              hipStream_t stream) {
    const float* x  = (const float*)d_in[0];
    const float* w1 = (const float*)d_in[1];
    const float* g1 = (const float*)d_in[2];
    const float* b1 = (const float*)d_in[3];
    const float* w2 = (const float*)d_in[4];
    const float* g2 = (const float*)d_in[5];
    const float* b2 = (const float*)d_in[6];
    float* out = (float*)d_out;

    char* ws = (char*)d_ws;
    uint32_t* s1  = (uint32_t*)(ws + OFF_S1);
    uint32_t* s2  = (uint32_t*)(ws + OFF_S2);
    uint32_t* wp1 = (uint32_t*)(ws + OFF_WP1);
    uint32_t* wp2 = (uint32_t*)(ws + OFF_WP2);
    unsigned long long* sq1 = (unsigned long long*)(ws + OFF_SQ1);
    unsigned long long* sq2 = (unsigned long long*)(ws + OFF_SQ2);
    int* sum1 = (int*)(ws + OFF_SUM1);
    int* sum2 = (int*)(ws + OFF_SUM2);

    k_setup<<<132, 256, 0, stream>>>((const uint32_t*)w1, (const uint32_t*)w2, ws);
    k_packx<<<784, 256, 0, stream>>>((const uint32_t*)x, s1);
    k_stats<<<3584, 448, 0, stream>>>(s1, wp1, sum1, sq1);
    k_sign <<<3584, 448, 0, stream>>>(s1, wp1, sum1, sq1, g1, b1, s2);
    k_stats<<<3584, 448, 0, stream>>>(s2, wp2, sum2, sq2);
    k_res  <<<784, 256, 0, stream>>>(s2, wp2, sum2, sq2, g2, b2, x, out);
}

// Round 8
// 276.365 us; speedup vs baseline: 1.1582x; 1.1582x over previous
//
#include <hip/hip_runtime.h>
#include <stdint.h>

#define NB 16
#define CC 32
#define HH 224
#define WW 224
#define HWP (HH*WW)          // 50176
#define NHWP (NB*HWP)        // 802816
#define PW 226
#define PSZ (PW*PW)          // 51076 padded words per image

// workspace layout (bytes)
#define OFF_S1   0u
#define OFF_S2   3268864u    // 16*51076*4
#define OFF_WP1  6537728u
#define OFF_WP2  6538880u
#define OFF_SQ1  6540032u    // 16 bins x 32 x u64
#define OFF_SQ2  6544128u
#define OFF_SUM1 6548224u    // 16 bins x 32 x i32
#define OFF_SUM2 6550272u
#define OFF_BF1  6552320u    // decoded B-frags layer1: [9 taps][64 lanes] x 16B
#define OFF_BF2  6561536u    // layer2; end 6570752

typedef int v4i    __attribute__((ext_vector_type(4)));
typedef int i32x16 __attribute__((ext_vector_type(16)));

// ============ setup: pack weights, decode B-frags, zero stats, zero pad borders ============
__global__ void __launch_bounds__(256) k_setup(const uint32_t* __restrict__ w1,
                                               const uint32_t* __restrict__ w2,
                                               char* __restrict__ ws) {
    int t = blockIdx.x * 256 + threadIdx.x;
    if (t < 576) {
        const uint32_t* w = (t < 288) ? w1 : w2;
        uint32_t* o = (uint32_t*)(ws + ((t < 288) ? OFF_WP1 : OFF_WP2));
        int idx = (t < 288) ? t : t - 288;
        int oc = idx / 9, k = idx - oc * 9;
        uint32_t word = 0;
        for (int i = 0; i < 32; ++i)
            word |= (w[(oc * 32 + i) * 9 + k] >> 31) << i;
        o[idx] = word;
    } else if (t < 3648) {
        // 3072 words: sq1(1024) sq2(1024) sum1(512) sum2(512), contiguous
        ((uint32_t*)(ws + OFF_SQ1))[t - 576] = 0u;
    } else if (t >= 4096 && t < 32896) {
        int b = t - 4096;
        uint32_t* buf = (uint32_t*)(ws + ((b < 14400) ? OFF_S1 : OFF_S2));
        int bb = (b < 14400) ? b : b - 14400;
        int n = bb / 900;
        int e = bb - n * 900;
        int row, col;
        if (e < 226)      { row = 0;   col = e; }
        else if (e < 452) { row = 225; col = e - 226; }
        else { int k = e - 452; row = 1 + (k >> 1); col = (k & 1) ? 225 : 0; }
        buf[(size_t)n * PSZ + row * PW + col] = 0u;
    } else if (t >= 32896 && t < 34048) {
        // decoded +/-1 B-fragments: lane l of wave -> oc = l&31, k-base = (l>>5)*16
        int idx = t - 32896;
        int layer = idx / 576, rem = idx - layer * 576;
        int tap = rem / 64, lane = rem - tap * 64;
        int oc = lane & 31, kb = (lane >> 5) * 16;
        const uint32_t* w = layer ? w2 : w1;
        uint32_t dw[4];
        #pragma unroll
        for (int d = 0; d < 4; ++d) {
            uint32_t v = 0x01010101u;
            #pragma unroll
            for (int b = 0; b < 4; ++b) {
                uint32_t sgn = w[(oc * 32 + kb + 4 * d + b) * 9 + tap] >> 31;
                v ^= (0xFEu * sgn) << (8 * b);     // bit=1 -> byte 0xFF (-1)
            }
            dw[d] = v;
        }
        uint4* o = (uint4*)(ws + (layer ? OFF_BF2 : OFF_BF1));
        o[tap * 64 + lane] = make_uint4(dw[0], dw[1], dw[2], dw[3]);
    }
}

// ============ pack activation signs into padded layout ============
__global__ void __launch_bounds__(256) k_packx(const uint32_t* __restrict__ x,
                                               uint32_t* __restrict__ sp) {
    int t = blockIdx.x * 256 + threadIdx.x;        // 16 * 12544 threads, 4 px each
    int n = t / (HWP / 4);
    int rem4 = t - n * (HWP / 4);
    int px0 = rem4 * 4;
    int r = px0 / WW;
    int cw0 = px0 - r * WW;
    const uint32_t* xp = x + (size_t)n * CC * HWP + px0;
    uint32_t w0 = 0, w1 = 0, w2 = 0, w3 = 0;
    #pragma unroll
    for (int c = 0; c < 32; ++c) {
        uint4 v = *reinterpret_cast<const uint4*>(xp + (size_t)c * HWP);
        w0 |= (v.x >> 31) << c;
        w1 |= (v.y >> 31) << c;
        w2 |= (v.z >> 31) << c;
        w3 |= (v.w >> 31) << c;
    }
    uint32_t* op = sp + (size_t)n * PSZ + (r + 1) * PW + (cw0 + 1);
    op[0] = w0; op[1] = w1; op[2] = w2; op[3] = w3;
}

// ============ MFMA conv core ============
// Block = 448 threads = 7 waves; block handles one full row r of image n.
// Wave w computes out px [32w, 32w+32) x 32 oc via 9x mfma_i32_32x32x32_i8.
// A tile in LDS: 3 rows x 226 cols of decoded +/-1 i8 (pad -> 0), 48 B/px slot.
// A lane map (M=px): row = lane%32, k(ic) = 16*(lane/32) + [0..15]
// B lane map (N=oc): col = lane%32, k(ic) = 16*(lane/32) + [0..15]  (precomputed)
// C/D: col(oc) = lane&31, row(px) = (reg&3) + 8*(reg>>2) + 4*(lane>>5)
#define ASTRIDE 48
#define AROW (226*ASTRIDE)

__device__ __forceinline__ uint32_t spread4(uint32_t nib) {
    // 4 sign bits -> 4 bytes of +1 / -1 (0x01 / 0xFF); s*0xFE is byte-confined.
    uint32_t s = (nib & 1u) | ((nib & 2u) << 7) | ((nib & 4u) << 14) | ((nib & 8u) << 21);
    return 0x01010101u ^ (s * 0xFEu);
}

__device__ __forceinline__ i32x16 conv_mfma(const uint32_t* __restrict__ sp,
                                            const v4i* __restrict__ bfp,
                                            int n, int r, char* At) {
    // stage + decode 3 rows incl. 1-px halo; out-of-image -> 0 bytes
    for (int s = threadIdx.x; s < 3 * 226; s += 448) {
        int dr = s / 226, cc = s - dr * 226;
        int srow = r - 1 + dr, scol = cc - 1;
        uint32_t d8[8];
        if (srow < 0 || srow >= HH || scol < 0 || scol >= WW) {
            #pragma unroll
            for (int i = 0; i < 8; ++i) d8[i] = 0u;
        } else {
            uint32_t w = sp[(size_t)n * PSZ + (srow + 1) * PW + (scol + 1)];
            #pragma unroll
            for (int i = 0; i < 8; ++i) d8[i] = spread4((w >> (4 * i)) & 0xFu);
        }
        uint32_t* p = (uint32_t*)(At + s * ASTRIDE);
        *(uint4*)(p)     = make_uint4(d8[0], d8[1], d8[2], d8[3]);
        *(uint4*)(p + 4) = make_uint4(d8[4], d8[5], d8[6], d8[7]);
    }

    // precomputed per-lane weight B-fragments (L2-hot broadcast reads)
    int l = threadIdx.x & 63;
    v4i bf[9];
    #pragma unroll
    for (int t = 0; t < 9; ++t) bf[t] = bfp[t * 64 + l];
    __syncthreads();

    int wavebase = (threadIdx.x >> 6) * 32;
    int base = (wavebase + (l & 31)) * ASTRIDE + (l >> 5) * 16;

    i32x16 acc = {0,0,0,0,0,0,0,0,0,0,0,0,0,0,0,0};
    #pragma unroll
    for (int dh = 0; dh < 3; ++dh) {
        #pragma unroll
        for (int dw = 0; dw < 3; ++dw) {
            v4i a = *reinterpret_cast<const v4i*>(At + base + dh * AROW + dw * ASTRIDE);
            acc = __builtin_amdgcn_mfma_i32_32x32x32_i8(a, bf[dh * 3 + dw], acc, 0, 0, 0);
        }
    }
    return acc;
}

// ============ conv (MFMA) + exact per-channel sum / sumsq into 16 bins ============
__global__ void __launch_bounds__(448) k_stats(const uint32_t* __restrict__ sp,
                                               const v4i* __restrict__ bfp,
                                               int* __restrict__ g_sum,
                                               unsigned long long* __restrict__ g_sq) {
    __shared__ __align__(16) char At[3 * 226 * ASTRIDE];
    __shared__ int ls[7][32], lq[7][32];

    int n = blockIdx.x / HH, r = blockIdx.x - n * HH;
    i32x16 acc = conv_mfma(sp, bfp, n, r, At);

    int l = threadIdx.x & 63;
    int s = 0, q = 0;
    #pragma unroll
    for (int g = 0; g < 16; ++g) { int c = acc[g]; s += c; q += c * c; }
    s += __shfl_xor(s, 32, 64);      // merge half-wave px groups; lane&31 owns oc
    q += __shfl_xor(q, 32, 64);
    int wid = threadIdx.x >> 6;
    if (l < 32) { ls[wid][l] = s; lq[wid][l] = q; }
    __syncthreads();
    if (threadIdx.x < 32) {
        int S = 0, Q = 0;
        #pragma unroll
        for (int w = 0; w < 7; ++w) { S += ls[w][threadIdx.x]; Q += lq[w][threadIdx.x]; }
        int bin = blockIdx.x & 15;
        atomicAdd(&g_sum[bin * 32 + threadIdx.x], S);
        atomicAdd(&g_sq[bin * 32 + threadIdx.x], (unsigned long long)(long long)Q);
    }
}

// ============ BN affine from 16-bin exact int stats ============
__device__ __forceinline__ void build_affine16(const int* __restrict__ g_sum,
                                               const unsigned long long* __restrict__ g_sq,
                                               const float* __restrict__ gamma,
                                               const float* __restrict__ beta,
                                               float* aL, float* dL) {
    if (threadIdx.x < 32) {
        int c = threadIdx.x;
        int Si = 0; unsigned long long Qu = 0;
        #pragma unroll
        for (int b = 0; b < 16; ++b) { Si += g_sum[b * 32 + c]; Qu += g_sq[b * 32 + c]; }
        double M = (double)NHWP;
        double mean = (double)Si / M;
        double ex2 = (double)(long long)Qu / M;
        double var = ex2 - mean * mean;
        double inv = 1.0 / sqrt(var + 1e-5);
        double aa = inv * (double)gamma[c];
        aL[c] = (float)aa;
        dL[c] = (float)((double)beta[c] - aa * mean);
    }
}

// ============ conv1 (MFMA) + BN1 + sign -> packed padded s2 via ballot ============
__global__ void __launch_bounds__(448) k_sign(const uint32_t* __restrict__ sp,
                                              const v4i* __restrict__ bfp,
                                              const int* __restrict__ g_sum,
                                              const unsigned long long* __restrict__ g_sq,
                                              const float* __restrict__ gamma,
                                              const float* __restrict__ beta,
                                              uint32_t* __restrict__ op) {
    __shared__ __align__(16) char At[3 * 226 * ASTRIDE];
    __shared__ float aL[32], dL[32];
    build_affine16(g_sum, g_sq, gamma, beta, aL, dL);

    int n = blockIdx.x / HH, r = blockIdx.x - n * HH;
    i32x16 acc = conv_mfma(sp, bfp, n, r, At);

    int l = threadIdx.x & 63;
    int wavebase = (threadIdx.x >> 6) * 32;
    float a = aL[l & 31], d = dL[l & 31];
    uint32_t* orow = op + (size_t)n * PSZ + (r + 1) * PW + 1 + wavebase;
    #pragma unroll
    for (int g = 0; g < 16; ++g) {
        float y = fmaf(a, (float)acc[g], d);
        unsigned long long b = __ballot((__float_as_uint(y) >> 31) != 0u);
        if (l == 0) {
            int pxr = (g & 3) + 8 * (g >> 2);   // lanes 0-31 px row; +4 for lanes 32-63
            orow[pxr]     = (uint32_t)b;
            orow[pxr + 4] = (uint32_t)(b >> 32);
        }
    }
}

// ============ conv2 (MFMA) + BN2 + residual -> f32 out (float4 IO) ============
// Lane's 16 accs = 4 groups of 4 consecutive px: px = wavebase + 8g + 4hi + j.
__global__ void __launch_bounds__(448) k_res(const uint32_t* __restrict__ sp,
                                             const v4i* __restrict__ bfp,
                                             const int* __restrict__ g_sum,
                                             const unsigned long long* __restrict__ g_sq,
                                             const float* __restrict__ gamma,
                                             const float* __restrict__ beta,
                                             const float* __restrict__ x,
                                             float* __restrict__ out) {
    __shared__ __align__(16) char At[3 * 226 * ASTRIDE];
    __shared__ float aL[32], dL[32];
    build_affine16(g_sum, g_sq, gamma, beta, aL, dL);

    int n = blockIdx.x / HH, r = blockIdx.x - n * HH;
    i32x16 acc = conv_mfma(sp, bfp, n, r, At);

    int l = threadIdx.x & 63;
    int oc = l & 31, hi = l >> 5;
    int wavebase = (threadIdx.x >> 6) * 32;
    float a = aL[oc], d = dL[oc];
    size_t rowoff = (size_t)n * CC * HWP + (size_t)oc * HWP + (size_t)r * WW;
    #pragma unroll
    for (int g = 0; g < 4; ++g) {
        int px0 = wavebase + 8 * g + 4 * hi;
        float4 xv = *reinterpret_cast<const float4*>(x + rowoff + px0);
        float4 ov;
        ov.x = xv.x + fmaf(a, (float)acc[4 * g + 0], d);
        ov.y = xv.y + fmaf(a, (float)acc[4 * g + 1], d);
        ov.z = xv.z + fmaf(a, (float)acc[4 * g + 2], d);
        ov.w = xv.w + fmaf(a, (float)acc[4 * g + 3], d);
        *reinterpret_cast<float4*>(out + rowoff + px0) = ov;
    }
}

extern "C" void kernel_launch(void* const* d_in, const int* in_sizes, int n_in,
                              void* d_out, int out_size, void* d_ws, size_t ws_size,
                              hipStream_t stream) {
    const float* x  = (const float*)d_in[0];
    const float* w1 = (const float*)d_in[1];
    const float* g1 = (const float*)d_in[2];
    const float* b1 = (const float*)d_in[3];
    const float* w2 = (const float*)d_in[4];
    const float* g2 = (const float*)d_in[5];
    const float* b2 = (const float*)d_in[6];
    float* out = (float*)d_out;

    char* ws = (char*)d_ws;
    uint32_t* s1  = (uint32_t*)(ws + OFF_S1);
    uint32_t* s2  = (uint32_t*)(ws + OFF_S2);
    const v4i* bf1 = (const v4i*)(ws + OFF_BF1);
    const v4i* bf2 = (const v4i*)(ws + OFF_BF2);
    unsigned long long* sq1 = (unsigned long long*)(ws + OFF_SQ1);
    unsigned long long* sq2 = (unsigned long long*)(ws + OFF_SQ2);
    int* sum1 = (int*)(ws + OFF_SUM1);
    int* sum2 = (int*)(ws + OFF_SUM2);

    k_setup<<<134, 256, 0, stream>>>((const uint32_t*)w1, (const uint32_t*)w2, ws);
    k_packx<<<784, 256, 0, stream>>>((const uint32_t*)x, s1);
    k_stats<<<3584, 448, 0, stream>>>(s1, bf1, sum1, sq1);
    k_sign <<<3584, 448, 0, stream>>>(s1, bf1, sum1, sq1, g1, b1, s2);
    k_stats<<<3584, 448, 0, stream>>>(s2, bf2, sum2, sq2);
    k_res  <<<3584, 448, 0, stream>>>(s2, bf2, sum2, sq2, g2, b2, x, out);
}